// Round 16
// baseline (13662.740 us; speedup 1.0000x reference)
//
#include <hip/hip_runtime.h>

// ESN recurrence on MI355X: h_t = tanh(x_t @ W_in^T + h_{t-1} @ W_res^T)
// B=64, T=512, I=128, H=2048. Persistent kernel, 256 WGs (1/CU).
// R16 = R15's one-XCD-clique topology, de-risked (R15's failure signature =
// silent launch rejection; suspects: 390+ VGPRs and/or 1MB d_ws — both fixed):
//  - decomposition: bg = wg&7 (8 batch-groups x 8 batches), j = wg>>3
//    (32 row-groups x 64 rows). Under the XCD map (xcd = wg&7) all 32 WGs of
//    a bg share one XCD -> h exchange is XCD-local through the L2.
//  - W_res slice SPLIT: row-tiles 0-1 (32 rows) in LDS (R12-proven layout),
//    row-tiles 2-3 in registers breg[16][2] (128 VGPRs). Total ~290 VGPRs.
//  - depth-2 h ping-pong, 1-bit in-band tag in fp16 mantissa LSB, bit
//    (t>>1)&1 (exact R10-R14-proven scheme, 0.5 MB d_ws).
//  - producer: tagged u32 relaxed-agent write-through stores (fire&forget).
//  - consumer: 16 coalesced sc0 loads (local L2) + tag validate + masked
//    retry; escalate to sc0 sc1 after 16 rounds (progress guaranteed even if
//    the XCD map is wrong). No flags, no fences, no leaders.
//  - coop-launch return code CHECKED; fallback plain launch (1 block/CU
//    resources => co-resident in practice; protocol assumes no ordering).

#define B_ 64
#define T_ 512
#define I_ 128
#define H_ 2048
#define NWG 256
#define ROWS 64          // output rows per WG (4 row-tiles of 16)
#define BATS 8           // batches per WG
#define WPAD 2056        // 2048 + 8 halves row pad (LDS W_res rows 0..31)
#define PPITCH 9         // partials pitch: 8 batches + 1 pad

typedef _Float16 f16;
typedef f16 f16x8 __attribute__((ext_vector_type(8)));
typedef float f32x4 __attribute__((ext_vector_type(4)));
typedef unsigned long long u64;
typedef unsigned int u32;
typedef unsigned short u16;
typedef u32 u32x4 __attribute__((ext_vector_type(4)));

#define TAG32 0x00010001u            // mantissa-LSB mask, 2 halves per dword

// LDS layout (bytes): Wres rows 0..31: 32*WPAD*2 = 131584 ; part: 4*64*9*4 = 9216
#define LDS_WRES   0
#define LDS_PART   131584
#define LDS_TOTAL  (131584 + 9216)

__device__ __forceinline__ float fast_tanh(float s)
{
    float ax = __builtin_fminf(__builtin_fabsf(s), 9.0f);
    float e  = __expf(-2.0f * ax);
    float r  = (1.0f - e) / (1.0f + e);
    return __builtin_copysignf(r, s);
}

extern "C" __global__ __launch_bounds__(256, 1)
void esn_kernel(const float* __restrict__ x, const float* __restrict__ Win,
                const float* __restrict__ Wres, float* __restrict__ out,
                u16* ht0, u16* ht1)
{
    extern __shared__ char lds[];
    f16*   Wr   = (f16*)(lds + LDS_WRES);    // [32][WPAD] rows r0..r0+31
    float* part = (float*)(lds + LDS_PART);  // [4][64][PPITCH]

    const int tid  = threadIdx.x;
    const int wg   = blockIdx.x;
    const int bg   = wg & 7;        // batch group 0..7 (assumed XCD id)
    const int j    = wg >> 3;       // row group 0..31
    const int r0   = j * ROWS;
    const int b0   = bg * BATS;
    const int wv   = tid >> 6;      // wave 0..3 (k-range [wv*512,+512))
    const int lane = tid & 63;
    const int lm   = lane & 15;     // B n (row-in-tile) / A m (batch, &7)
    const int quad = lane >> 4;     // k sub-offset; C row = quad*4+reg

    // ---- one-time: W_res rows r0..r0+31 (row-tiles 0,1) -> LDS fp16 ----
    for (int idx = tid; idx < 32 * (H_ / 4); idx += 256) {
        int r  = idx >> 9;          // 512 float4 per row
        int c4 = idx & 511;
        const float4 v = ((const float4*)(Wres + (size_t)(r0 + r) * H_))[c4];
        f16* dst = Wr + r * WPAD + c4 * 4;
        dst[0] = (f16)v.x; dst[1] = (f16)v.y; dst[2] = (f16)v.z; dst[3] = (f16)v.w;
    }
    // ---- one-time: W_res row-tiles 2,3 -> register B-fragments ----
    // frag(ks,rt): B[k][n]: n = r0 + (rt+2)*16 + lm, k = wv*512+ks*32+quad*8+jj
    f16x8 breg[16][2];
    #pragma unroll
    for (int ks = 0; ks < 16; ks++) {
        #pragma unroll
        for (int rt = 0; rt < 2; rt++) {
            const float* p = Wres + (size_t)(r0 + (rt + 2) * 16 + lm) * H_
                           + (wv << 9) + (ks << 5) + (quad << 3);
            float4 v0 = *(const float4*)(p);
            float4 v1 = *(const float4*)(p + 4);
            f16x8 f;
            f[0] = (f16)v0.x; f[1] = (f16)v0.y; f[2] = (f16)v0.z; f[3] = (f16)v0.w;
            f[4] = (f16)v1.x; f[5] = (f16)v1.y; f[6] = (f16)v1.z; f[7] = (f16)v1.w;
            breg[ks][rt] = f;
        }
    }
    // ---- one-time: W_in B-fragments (all 4 row-tiles), fp16 hi+lo ----
    f16x8 wih[4], wil[4];
    #pragma unroll
    for (int rt = 0; rt < 4; rt++) {
        const float* p = Win + (size_t)(r0 + rt * 16 + lm) * I_
                       + (wv << 5) + (quad << 3);
        float4 v0 = *(const float4*)(p);
        float4 v1 = *(const float4*)(p + 4);
        float vv[8] = {v0.x, v0.y, v0.z, v0.w, v1.x, v1.y, v1.z, v1.w};
        f16x8 h, l;
        #pragma unroll
        for (int q = 0; q < 8; q++) {
            f16 hi = (f16)vv[q];
            h[q] = hi;
            l[q] = (f16)(vv[q] - (float)hi);
        }
        wih[rt] = h;
        wil[rt] = l;
    }
    __syncthreads();

    for (int t = 0; t < T_; t++) {
        const u16* hrd = (t & 1) ? ht1 : ht0;   // fresh carries bit (t>>1)&1
        u16*       hwr = (t & 1) ? ht0 : ht1;   // write bit ((t+1)>>1)&1
        const u32  E32 = ((t >> 1) & 1) ? TAG32 : 0u;

        f32x4 acc[4] = {{0,0,0,0}, {0,0,0,0}, {0,0,0,0}, {0,0,0,0}};

        // lane's h base (bytes): batch row 4096 B, wave k 1024 B, quad 16 B
        const u64 hb = (u64)hrd + ((u64)(b0 + (lm & 7)) << 12) + (wv << 10)
                     + (quad << 4);

        // ---- issue 16 h A-frag loads, L2-local (sc0) ----
        u32x4 a[16];
        #pragma unroll
        for (int ks = 0; ks < 16; ks++) {
            asm volatile("global_load_dwordx4 %0, %1, off sc0"
                         : "=&v"(a[ks]) : "v"(hb + (u64)(ks * 64)));
        }

        // ---- x_t @ W_in^T (overlaps h-load latency) ----
        {
            const float* xp = x + ((size_t)(b0 + (lm & 7)) * T_ + t) * I_
                            + (wv << 5) + (quad << 3);
            float4 v0 = *(const float4*)(xp);
            float4 v1 = *(const float4*)(xp + 4);
            float xf[8] = {v0.x, v0.y, v0.z, v0.w, v1.x, v1.y, v1.z, v1.w};
            f16x8 xhi, xlo;
            #pragma unroll
            for (int q = 0; q < 8; q++) {
                f16 hi = (f16)xf[q];
                xhi[q] = hi;
                xlo[q] = (f16)(xf[q] - (float)hi);
            }
            #pragma unroll
            for (int rt = 0; rt < 4; rt++) {
                acc[rt] = __builtin_amdgcn_mfma_f32_16x16x32_f16(xhi, wih[rt], acc[rt], 0, 0, 0);
                acc[rt] = __builtin_amdgcn_mfma_f32_16x16x32_f16(xlo, wih[rt], acc[rt], 0, 0, 0);
                acc[rt] = __builtin_amdgcn_mfma_f32_16x16x32_f16(xhi, wil[rt], acc[rt], 0, 0, 0);
            }
        }

        // ---- wait, validate in-band tags, L2-local masked retry ----
        asm volatile("s_waitcnt vmcnt(0)" ::: "memory");
        int rounds = 0;
        for (;;) {
            u32 bad = 0;
            #pragma unroll
            for (int ks = 0; ks < 16; ks++)
                #pragma unroll
                for (int e = 0; e < 4; e++)
                    bad |= (a[ks][e] & TAG32) ^ E32;
            if (__all(bad == 0)) break;
            ++rounds;
            if (bad) {                       // only stale lanes re-load
                __builtin_amdgcn_s_sleep(1);
                if (rounds < 16) {           // fast path: local L2
                    #pragma unroll
                    for (int ks = 0; ks < 16; ks++)
                        asm volatile("global_load_dwordx4 %0, %1, off sc0"
                                     : "=&v"(a[ks]) : "v"(hb + (u64)(ks * 64)));
                } else {                     // safety valve: coherence point
                    #pragma unroll
                    for (int ks = 0; ks < 16; ks++)
                        asm volatile("global_load_dwordx4 %0, %1, off sc0 sc1"
                                     : "=&v"(a[ks]) : "v"(hb + (u64)(ks * 64)));
                }
            }
            asm volatile("s_waitcnt vmcnt(0)" ::: "memory");
        }

        // ---- h_{t-1} @ W_res^T: 64 MFMAs (2 LDS row-tiles + 2 reg tiles) ----
        {
            const f16* w0 = Wr + lm * WPAD + (wv << 9) + (quad << 3);
            const f16* w1 = Wr + (lm + 16) * WPAD + (wv << 9) + (quad << 3);
            #pragma unroll
            for (int ks = 0; ks < 16; ks++) {
                f16x8 af;
                #pragma unroll
                for (int e = 0; e < 4; e++)
                    ((u32*)&af)[e] = a[ks][e] & ~TAG32;   // clear tag (<=1 ulp)
                f16x8 bf0 = *(const f16x8*)(w0 + ks * 32);   // ds_read_b128
                f16x8 bf1 = *(const f16x8*)(w1 + ks * 32);
                acc[0] = __builtin_amdgcn_mfma_f32_16x16x32_f16(af, bf0, acc[0], 0, 0, 0);
                acc[1] = __builtin_amdgcn_mfma_f32_16x16x32_f16(af, bf1, acc[1], 0, 0, 0);
                acc[2] = __builtin_amdgcn_mfma_f32_16x16x32_f16(af, breg[ks][0], acc[2], 0, 0, 0);
                acc[3] = __builtin_amdgcn_mfma_f32_16x16x32_f16(af, breg[ks][1], acc[3], 0, 0, 0);
            }
        }

        // ---- cross-wave K-reduce: partials to LDS ----
        // C layout: col=lm -> row-in-tile, row=quad*4+reg -> batch (valid < 8)
        if (quad < 2) {
            #pragma unroll
            for (int rt = 0; rt < 4; rt++) {
                float* pw = part + ((wv * ROWS + rt * 16 + lm) * PPITCH) + quad * 4;
                pw[0] = acc[rt][0];
                pw[1] = acc[rt][1];
                pw[2] = acc[rt][2];
                pw[3] = acc[rt][3];
            }
        }
        __syncthreads();

        // ---- reduce 4 waves + tanh + store: b = tid>>5, rr = (tid&31)*2 ----
        {
            const int b  = tid >> 5;
            const int rr = (tid & 31) * 2;
            float s0 = 0.f, s1 = 0.f;
            #pragma unroll
            for (int w = 0; w < 4; w++) {
                s0 += part[(w * ROWS + rr)     * PPITCH + b];
                s1 += part[(w * ROWS + rr + 1) * PPITCH + b];
            }
            s0 = fast_tanh(s0);
            s1 = fast_tanh(s1);
            if (t == T_ - 1) {
                float* op = out + (size_t)(b0 + b) * H_ + r0 + rr;
                op[0] = s0;
                op[1] = s1;
            } else {
                union { f16 f; u16 u; } c0, c1;
                c0.f = (f16)s0;
                c1.f = (f16)s1;
                const u16 bit = (u16)(((t + 1) >> 1) & 1);
                u32 pk = (u32)((c0.u & 0xFFFEu) | bit)
                       | ((u32)((c1.u & 0xFFFEu) | bit) << 16);
                // write-through to the coherence point; validity in-band
                __hip_atomic_store((u32*)(hwr + (size_t)(b0 + b) * H_ + r0 + rr),
                                   pk, __ATOMIC_RELAXED, __HIP_MEMORY_SCOPE_AGENT);
            }
        }

        // protect LDS partials from next step's writes (intra-WG only)
        __syncthreads();
    }
}

extern "C" void kernel_launch(void* const* d_in, const int* in_sizes, int n_in,
                              void* d_out, int out_size, void* d_ws, size_t ws_size,
                              hipStream_t stream)
{
    (void)in_sizes; (void)n_in; (void)out_size; (void)ws_size;
    const float* x    = (const float*)d_in[0];
    const float* Win  = (const float*)d_in[1];
    const float* Wres = (const float*)d_in[2];
    float* out = (float*)d_out;

    u16* ht0 = (u16*)d_ws;                        // [64][2048] fp16, LSB = tag
    u16* ht1 = ht0 + (size_t)B_ * H_;

    // ht0: 0x00 -> h_0 = 0, tag bit 0 fresh for t=0; ht1: 0x01 -> stale
    // until real h_1 (which carries bit (1>>1)&1 = 0... producers write bit
    // ((0+1)>>1)&1 = 0). Proven R10-R14.
    hipMemsetAsync(ht0, 0x00, (size_t)B_ * H_ * sizeof(u16), stream);
    hipMemsetAsync(ht1, 0x01, (size_t)B_ * H_ * sizeof(u16), stream);

    hipFuncSetAttribute((const void*)esn_kernel,
                        hipFuncAttributeMaxDynamicSharedMemorySize, LDS_TOTAL);

    void* args[] = {(void*)&x, (void*)&Win, (void*)&Wres, (void*)&out,
                    (void*)&ht0, (void*)&ht1};
    hipError_t err = hipLaunchCooperativeKernel((const void*)esn_kernel,
                                                dim3(NWG), dim3(256), args,
                                                LDS_TOTAL, stream);
    if (err != hipSuccess) {
        // Fallback: plain launch. 256 blocks at 1-block/CU resources are
        // co-resident on 256 CUs in practice; the tag protocol assumes no
        // dispatch order and has an L3 escalation valve.
        esn_kernel<<<dim3(NWG), dim3(256), LDS_TOTAL, stream>>>(
            x, Win, Wres, out, ht0, ht1);
    }
}